// Round 2
// baseline (145.343 us; speedup 1.0000x reference)
//
#include <hip/hip_runtime.h>
#include <hip/hip_cooperative_groups.h>
#include <math.h>

#define N_OCT  32
#define N_SMP  32768
#define N_PAIR 64          // B*E = 4*16
#define BPP    16          // blocks per pair: 2048 samples/block, 8/thread
#define NBLK   (N_PAIR * BPP)   // 1024 blocks = 4/CU -> cooperative-residency safe

// ---------------------------------------------------------------------------
// R8: single cooperative kernel. osc+norm fused across a grid.sync() so the
// per-pair max never forces a second pass over out:
//   - acc[8] stays in registers across the barrier; out is written ONCE,
//     already normalized (saves 16.8 MB traffic + one launch gap vs R7).
//   - BPP 32->16: 1024 blocks, 4 blocks/CU co-residency (VGPR cap 128 via
//     __launch_bounds__(256,4) -- huge margin, ~50 used), 8 independent FMA
//     chains hide v_sin latency, half the prologue executions.
//   - R7's active-octave truncation kept: Nyquist mask is a monotone prefix
//     (harmonic ramp), masked octaves are exact +0 -> bit-identical skip.
//   - Prologue keeps the reference's EXACT sequential fp32 cumsum rounding.
//   - R4 lesson (420us per-block device fences) avoided: ONE grid barrier,
//     one tid0 threadfence per block.
// ---------------------------------------------------------------------------
__global__ __launch_bounds__(256, 4) void f0res_fused(
    const float* __restrict__ f0_in,
    const float* __restrict__ dec_in,
    const float* __restrict__ fs_in,
    float* __restrict__ out,
    float* __restrict__ bmax)        // [N_PAIR][BPP]
{
    __shared__ __align__(16) float sw[N_OCT];
    __shared__ __align__(16) float sa[N_OCT];
    __shared__ int s_ng;
    __shared__ float wm[4];

    const int pair = blockIdx.x >> 4;
    const int blk  = blockIdx.x & (BPP - 1);
    const int tid  = threadIdx.x;

    // ---- in-block setup (lanes 0-31 of wave 0) ----
    if (tid < N_OCT) {
        const float minf   = (float)(20.0 / 11025.0);
        const float frange = (float)(3000.0 / 11025.0 - 20.0 / 11025.0);
        const float pif    = 3.14159265358979323846f;
        const float INV2PI = 0.15915494309189535f;

        float f0 = fabsf(f0_in[pair]);
        float fs = fs_in[pair];
        float x  = dec_in[pair];

        float s1 = 1.0f / (1.0f + expf(-x));      // double sigmoid (ref quirk)
        float s2 = 1.0f / (1.0f + expf(-s1));
        float d  = 0.01f + s2 * (float)(0.99 * 0.99);
        float ld = logf(d + 1e-12f);
        float f0p = (minf + f0 * frange) * pif;

        // sequential fp32 cumsums — bit-match the reference rounding order
        float fac = 0.0f, acl = 0.0f, myfac = 0.0f, myacl = 0.0f;
#pragma unroll
        for (int o = 0; o < N_OCT; ++o) {
            fac += fs;
            acl += ld;
            if (o == tid) { myfac = fac; myacl = acl; }
        }
        float f0s = f0p * myfac;
        const bool act = (f0s < 1.0f);            // monotone -> prefix mask
        sw[tid] = act ? f0s * INV2PI : 0.0f;      // revolutions; sin(0)=0
        sa[tid] = expf(myacl);                    // d^(o+1)

        unsigned long long bal = __ballot(act);   // lanes 32-63 inactive -> 0
        if (tid == 0) s_ng = (__popcll(bal) + 3) >> 2;   // active float4 groups
    }
    __syncthreads();

    const int ng = s_ng;                          // uniform per block

    const int s0 = (blk << 11) + tid;             // samples s0 + k*256, k=0..7
    float t[8], acc[8];
#pragma unroll
    for (int k = 0; k < 8; ++k) {                 // t = s+1, exact in fp32
        t[k]   = (float)(s0 + 1 + (k << 8));
        acc[k] = 0.0f;
    }

    const float4* w4 = (const float4*)sw;
    const float4* a4 = (const float4*)sa;
    for (int i = 0; i < ng; ++i) {
        const float4 wv = w4[i];                  // ds_read_b128 broadcast
        const float4 av = a4[i];
        const float wr[4] = { wv.x, wv.y, wv.z, wv.w };
        const float ar[4] = { av.x, av.y, av.z, av.w };
#pragma unroll
        for (int j = 0; j < 4; ++j) {
            const float w = wr[j], a = ar[j];
#pragma unroll
            for (int k = 0; k < 8; ++k)           // static idx -> registers
                acc[k] = fmaf(a, __builtin_amdgcn_sinf(
                                     __builtin_amdgcn_fractf(w * t[k])), acc[k]);
        }
    }

    // ---- block max -> bmax (one plain store per block) ----
    float av_ = 0.0f;
#pragma unroll
    for (int k = 0; k < 8; ++k) av_ = fmaxf(av_, fabsf(acc[k]));
#pragma unroll
    for (int m = 32; m >= 1; m >>= 1)
        av_ = fmaxf(av_, __shfl_xor(av_, m, 64));
    if ((tid & 63) == 0) wm[tid >> 6] = av_;
    __syncthreads();
    if (tid == 0) {
        bmax[(pair << 4) + blk] =
            fmaxf(fmaxf(wm[0], wm[1]), fmaxf(wm[2], wm[3]));
        __threadfence();                          // publish before barrier
    }

    cooperative_groups::this_grid().sync();       // one grid-wide barrier

    // ---- pair max (16 values, replicated 4x per wave), normalize, store ----
    float v = bmax[(pair << 4) + (tid & 15)];
#pragma unroll
    for (int m = 8; m >= 1; m >>= 1)
        v = fmaxf(v, __shfl_xor(v, m, 64));       // every lane = pair max
    const float inv = 1.0f / (v + 1e-8f);

    float* op = out + pair * N_SMP + s0;
#pragma unroll
    for (int k = 0; k < 8; ++k)
        op[k << 8] = acc[k] * inv;                // single, normalized write
}

extern "C" void kernel_launch(void* const* d_in, const int* in_sizes, int n_in,
                              void* d_out, int out_size, void* d_ws, size_t ws_size,
                              hipStream_t stream) {
    const float* f0  = (const float*)d_in[0];
    const float* dec = (const float*)d_in[1];
    const float* fs  = (const float*)d_in[2];
    float* out  = (float*)d_out;
    float* bmax = (float*)d_ws;                   // 64*16 floats

    void* args[] = { (void*)&f0, (void*)&dec, (void*)&fs,
                     (void*)&out, (void*)&bmax };
    hipLaunchCooperativeKernel((void*)f0res_fused,
                               dim3(NBLK), dim3(256), args, 0, stream);
}

// Round 3
// 71.709 us; speedup vs baseline: 2.0268x; 2.0268x over previous
//
#include <hip/hip_runtime.h>
#include <math.h>

#define N_OCT  32
#define N_SMP  32768
#define N_PAIR 64          // B*E = 4*16
#define BPP    32          // blocks per pair: 1024 samples/block, 4/thread

// ---------------------------------------------------------------------------
// R9: eliminate ALL workspace use. The 256 MB d_ws re-poison fill (268 MB
// write, 41 us at 82% HBM peak) is the single largest dispatch in the timed
// graph — and we were using 4 KB of that workspace just to ferry per-block
// maxes. fmaxf over non-NaN data is exactly associative, so kernel 2 can
// recompute each pair's max straight from `out` (L2/L3-hot, just written)
// with one 1024-thread block per pair. Bit-identical output to R7.
//   - osc: unchanged R7 body (active-octave truncation, 4 FMA chains,
//     exact sequential-cumsum prologue), minus the bmax epilogue.
//   - norm: 64 blocks x 1024 threads; 8 float4 loads/thread into registers,
//     shfl+LDS max tree, scale, store. No cross-block traffic, no ws.
//   - R8 lesson: grid-scope sync costs ~65 us on MI355X (1024 spinners on
//     one line across 8 non-coherent XCD L2s) — kernel boundary is cheaper.
// ---------------------------------------------------------------------------
__global__ __launch_bounds__(256) void f0res_osc(
    const float* __restrict__ f0_in,
    const float* __restrict__ dec_in,
    const float* __restrict__ fs_in,
    float* __restrict__ out)
{
    __shared__ __align__(16) float sw[N_OCT];
    __shared__ __align__(16) float sa[N_OCT];
    __shared__ int s_ng;

    const int pair = blockIdx.x >> 5;
    const int blk  = blockIdx.x & (BPP - 1);
    const int tid  = threadIdx.x;

    // ---- in-block setup (lanes 0-31 of wave 0) ----
    if (tid < N_OCT) {
        const float minf   = (float)(20.0 / 11025.0);
        const float frange = (float)(3000.0 / 11025.0 - 20.0 / 11025.0);
        const float pif    = 3.14159265358979323846f;
        const float INV2PI = 0.15915494309189535f;

        float f0 = fabsf(f0_in[pair]);
        float fs = fs_in[pair];
        float x  = dec_in[pair];

        float s1 = 1.0f / (1.0f + expf(-x));      // double sigmoid (ref quirk)
        float s2 = 1.0f / (1.0f + expf(-s1));
        float d  = 0.01f + s2 * (float)(0.99 * 0.99);
        float ld = logf(d + 1e-12f);
        float f0p = (minf + f0 * frange) * pif;

        // sequential fp32 cumsums — bit-match the reference rounding order
        float fac = 0.0f, acl = 0.0f, myfac = 0.0f, myacl = 0.0f;
#pragma unroll
        for (int o = 0; o < N_OCT; ++o) {
            fac += fs;
            acl += ld;
            if (o == tid) { myfac = fac; myacl = acl; }
        }
        float f0s = f0p * myfac;
        const bool act = (f0s < 1.0f);            // monotone -> prefix mask
        sw[tid] = act ? f0s * INV2PI : 0.0f;      // revolutions; sin(0)=0
        sa[tid] = expf(myacl);                    // d^(o+1)

        unsigned long long bal = __ballot(act);   // lanes 32-63 inactive -> 0
        if (tid == 0) s_ng = (__popcll(bal) + 3) >> 2;   // active float4 groups
    }
    __syncthreads();

    const int ng = s_ng;                          // uniform per block

    const int   s0 = (blk << 10) + tid;           // samples s0 + {0,256,512,768}
    const float t0 = (float)(s0 + 1);             // t = s+1, exact in fp32
    const float t1 = (float)(s0 + 257);
    const float t2 = (float)(s0 + 513);
    const float t3 = (float)(s0 + 769);

    float acc0 = 0.0f, acc1 = 0.0f, acc2 = 0.0f, acc3 = 0.0f;

    const float4* w4 = (const float4*)sw;
    const float4* a4 = (const float4*)sa;
    for (int i = 0; i < ng; ++i) {
        const float4 wv = w4[i];                  // ds_read_b128 broadcast
        const float4 av = a4[i];
        const float wr[4] = { wv.x, wv.y, wv.z, wv.w };
        const float ar[4] = { av.x, av.y, av.z, av.w };
#pragma unroll
        for (int j = 0; j < 4; ++j) {
            const float w = wr[j], a = ar[j];
            acc0 = fmaf(a, __builtin_amdgcn_sinf(__builtin_amdgcn_fractf(w * t0)), acc0);
            acc1 = fmaf(a, __builtin_amdgcn_sinf(__builtin_amdgcn_fractf(w * t1)), acc1);
            acc2 = fmaf(a, __builtin_amdgcn_sinf(__builtin_amdgcn_fractf(w * t2)), acc2);
            acc3 = fmaf(a, __builtin_amdgcn_sinf(__builtin_amdgcn_fractf(w * t3)), acc3);
        }
    }

    float* op = out + pair * N_SMP + s0;
    op[0]   = acc0;
    op[256] = acc1;
    op[512] = acc2;
    op[768] = acc3;
}

// ---------------------------------------------------------------------------
// Kernel 2: one block per pair. Recompute the pair max from out (exact:
// fmaxf is associative for non-NaN), normalize, store. 8 float4/thread kept
// in registers; reads are L2/L3-hot (out was just written).
// ---------------------------------------------------------------------------
__global__ __launch_bounds__(1024) void f0res_norm(float* __restrict__ out)
{
    const int pair = blockIdx.x;
    const int tid  = threadIdx.x;

    float4* o4 = (float4*)(out + pair * N_SMP);   // 8192 float4 per pair

    float4 v[8];
    float m = 0.0f;
#pragma unroll
    for (int k = 0; k < 8; ++k) {
        v[k] = o4[tid + (k << 10)];
        m = fmaxf(m, fmaxf(fmaxf(fabsf(v[k].x), fabsf(v[k].y)),
                           fmaxf(fabsf(v[k].z), fabsf(v[k].w))));
    }

    // wave max (64 lanes), then 16 wave leaders -> LDS -> wave 0 -> broadcast
#pragma unroll
    for (int s = 32; s >= 1; s >>= 1)
        m = fmaxf(m, __shfl_xor(m, s, 64));
    __shared__ float wm[16];
    __shared__ float smx;
    if ((tid & 63) == 0) wm[tid >> 6] = m;
    __syncthreads();
    if (tid < 64) {
        float x = (tid < 16) ? wm[tid] : 0.0f;
#pragma unroll
        for (int s = 8; s >= 1; s >>= 1)
            x = fmaxf(x, __shfl_xor(x, s, 64));
        if (tid == 0) smx = x;
    }
    __syncthreads();

    const float inv = 1.0f / (smx + 1e-8f);
#pragma unroll
    for (int k = 0; k < 8; ++k) {
        v[k].x *= inv; v[k].y *= inv; v[k].z *= inv; v[k].w *= inv;
        o4[tid + (k << 10)] = v[k];
    }
}

extern "C" void kernel_launch(void* const* d_in, const int* in_sizes, int n_in,
                              void* d_out, int out_size, void* d_ws, size_t ws_size,
                              hipStream_t stream) {
    const float* f0  = (const float*)d_in[0];
    const float* dec = (const float*)d_in[1];
    const float* fs  = (const float*)d_in[2];
    float* out = (float*)d_out;
    (void)d_ws; (void)ws_size;                    // workspace deliberately unused

    f0res_osc <<<N_PAIR * BPP, 256, 0, stream>>>(f0, dec, fs, out);
    f0res_norm<<<N_PAIR,      1024, 0, stream>>>(out);
}